// Round 3
// baseline (21.583 us; speedup 1.0000x reference)
//
#include <hip/hip_runtime.h>
#include <math.h>

#define D 2
#define HID 64
#define WIDTH 64
#define BATCH 262144
#define BLK 128  // WIDTH*D

typedef float v2f __attribute__((ext_vector_type(2)));

static __device__ __forceinline__ float fexp2(float x){ return __builtin_amdgcn_exp2f(x); }
static __device__ __forceinline__ float frcp(float x){ return __builtin_amdgcn_rcpf(x); }

// Packed Padé(5,4) tanh on clamp[-4,4]: x(945+105u+u^2)/(945+420u+15u^2), u=x^2.
// Max err ~2.3e-3 at |x|=4 (saturation), ~1e-4 interior. 8 pk-VALU + 2 rcp.
static __device__ __forceinline__ v2f tanh_pk(v2f x) {
    v2f lo = {-4.f, -4.f}, hi = {4.f, 4.f};
    v2f t = __builtin_elementwise_min(__builtin_elementwise_max(x, lo), hi);
    v2f u = t * t;
    v2f num = t * (945.f + u * (105.f + u));
    v2f den = 945.f + u * (420.f + 15.f * u);
    v2f r; r.x = frcp(den.x); r.y = frcp(den.y);
    return num * r;
}

// One fused kernel; each thread handles elements e1 = bid*512+tid and e2 = e1+256
// (stride-256 pair -> every load and store stream is perfectly coalesced).
__global__ __launch_bounds__(256) void fused_ode_kernel(
    const float* __restrict__ t,
    const float* __restrict__ hw1, const float* __restrict__ hb1,
    const float* __restrict__ hw2, const float* __restrict__ hb2,
    const float* __restrict__ hw3, const float* __restrict__ hb3,
    const float* __restrict__ z,       // [B,2]
    const float4* __restrict__ c4,     // [B] condition rows
    const float* __restrict__ cl_wz, const float* __restrict__ cl_bz,
    const float* __restrict__ cl_wc, const float* __restrict__ cl_bc,
    float* __restrict__ out)
{
    __shared__ float p1s[HID];
    __shared__ float p2s[HID];
    __shared__ float p3s[3*BLK + WIDTH];
    __shared__ __align__(16) float4 psA[WIDTH];  // {W0, W1, Bb, WUs}
    __shared__ __align__(8)  float2 psB[WIDTH];  // {Us0, Us1}
    __shared__ float sSum;                       // sum_w WUs

    const int tid = threadIdx.x;
    const int e1 = blockIdx.x * 512 + tid;
    const int e2 = e1 + 256;
    const float L2E = 1.4426950408889634f;

    // ---- issue batch loads early; HBM latency hides under the hypernet ----
    float2 zA = ((const float2*)z)[e1];
    float2 zB = ((const float2*)z)[e2];
    float4 cA = c4[e1];
    float4 cB = c4[e2];

    // ---------------- hypernet phase (per-block redundant) ----------------
    if (tid < HID) p1s[tid] = tanhf(t[0]*hw1[tid] + hb1[tid]);
    __syncthreads();

    if (tid < HID) {
        float a0=0.f, a1=0.f, a2=0.f, a3=0.f;
        const float4* row = (const float4*)(hw2 + tid*HID);
        #pragma unroll 4
        for (int k = 0; k < HID/4; ++k) {
            float4 r = row[k];
            a0 = fmaf(p1s[4*k+0], r.x, a0);
            a1 = fmaf(p1s[4*k+1], r.y, a1);
            a2 = fmaf(p1s[4*k+2], r.z, a2);
            a3 = fmaf(p1s[4*k+3], r.w, a3);
        }
        p2s[tid] = tanhf(hb2[tid] + ((a0+a1)+(a2+a3)));
    }
    __syncthreads();

    {   // 448 rows of w3: rows tid and 256+tid (tid<192)
        {
            float a0=0.f, a1=0.f, a2=0.f, a3=0.f;
            const float4* row = (const float4*)(hw3 + tid*HID);
            #pragma unroll 4
            for (int k = 0; k < HID/4; ++k) {
                float4 rv = row[k];
                a0 = fmaf(p2s[4*k+0], rv.x, a0);
                a1 = fmaf(p2s[4*k+1], rv.y, a1);
                a2 = fmaf(p2s[4*k+2], rv.z, a2);
                a3 = fmaf(p2s[4*k+3], rv.w, a3);
            }
            p3s[tid] = hb3[tid] + ((a0+a1)+(a2+a3));
        }
        if (tid < 192) {
            int r2 = 256 + tid;
            float a0=0.f, a1=0.f, a2=0.f, a3=0.f;
            const float4* row = (const float4*)(hw3 + r2*HID);
            #pragma unroll 4
            for (int k = 0; k < HID/4; ++k) {
                float4 rv = row[k];
                a0 = fmaf(p2s[4*k+0], rv.x, a0);
                a1 = fmaf(p2s[4*k+1], rv.y, a1);
                a2 = fmaf(p2s[4*k+2], rv.z, a2);
                a3 = fmaf(p2s[4*k+3], rv.w, a3);
            }
            p3s[r2] = hb3[r2] + ((a0+a1)+(a2+a3));
        }
    }
    __syncthreads();

    if (tid < WIDTH) {   // exactly wave 0
        const int w = tid;
        float W0 = p3s[2*w],        W1 = p3s[2*w+1];
        float U0 = p3s[BLK+2*w],    U1 = p3s[BLK+2*w+1];
        float G0 = p3s[2*BLK+2*w],  G1 = p3s[2*BLK+2*w+1];
        float Bb = p3s[3*BLK+w];
        U0 *= frcp(1.0f + fexp2(-G0*L2E));
        U1 *= frcp(1.0f + fexp2(-G1*L2E));
        float Us0 = U0 * (1.0f/WIDTH);
        float Us1 = U1 * (1.0f/WIDTH);
        float WUs = W0*Us0 + W1*Us1;
        psA[w] = make_float4(W0, W1, Bb, WUs);
        psB[w] = make_float2(Us0, Us1);
        float s = WUs;
        #pragma unroll
        for (int off = 32; off > 0; off >>= 1) s += __shfl_down(s, off);
        if (w == 0) sSum = s;
    }
    __syncthreads();

    // ---------------- batch phase (packed over the {A,B} element pair) ----------------
    // small uniform weights
    float wz[8], wc[16], bbv[4];
    #pragma unroll
    for (int j = 0; j < 8;  ++j) wz[j] = cl_wz[j];
    #pragma unroll
    for (int j = 0; j < 16; ++j) wc[j] = cl_wc[j];
    #pragma unroll
    for (int j = 0; j < 4;  ++j) bbv[j] = cl_bz[j] + cl_bc[j];

    v2f zv0 = {zA.x, zB.x}, zv1 = {zA.y, zB.y};
    v2f cv0 = {cA.x, cB.x}, cv1 = {cA.y, cB.y};
    v2f cv2 = {cA.z, cB.z}, cv3 = {cA.w, cB.w};

    v2f act[4];
    #pragma unroll
    for (int j = 0; j < 4; ++j) {
        v2f a = zv0*wz[2*j] + zv1*wz[2*j+1] + bbv[j];
        a = a + cv0*wc[4*j] + cv1*wc[4*j+1] + cv2*wc[4*j+2] + cv3*wc[4*j+3];
        act[j] = a;
    }
    v2f th0 = tanh_pk(act[0]);
    v2f th1 = tanh_pk(act[1]);
    v2f sg0 = 0.5f + 0.5f*tanh_pk(act[2]*0.5f);
    v2f sg1 = 0.5f + 0.5f*tanh_pk(act[3]*0.5f);
    v2f zc0 = th0 * sg0;
    v2f zc1 = th1 * sg1;

    // condition copy out (coalesced, fire-and-forget)
    float4* oc = (float4*)(out + 3*(size_t)BATCH);
    oc[e1] = cA;
    oc[e2] = cB;

    v2f acc0 = {0.f,0.f}, acc1 = {0.f,0.f}, tr = {0.f,0.f};
    #pragma unroll 8
    for (int w = 0; w < WIDTH; ++w) {
        float4 pa = psA[w];          // uniform LDS broadcast
        float2 pb = psB[w];
        v2f pre = zc0*pa.x + zc1*pa.y + pa.z;
        v2f h = tanh_pk(pre);
        acc0 += h * pb.x;
        acc1 += h * pb.y;
        tr   += (h*h) * pa.w;
    }
    float s = sSum;

    ((float2*)out)[e1] = make_float2(acc0.x, acc1.x);   // dz_dt
    ((float2*)out)[e2] = make_float2(acc0.y, acc1.y);
    float* dl = out + 2*(size_t)BATCH;
    dl[e1] = tr.x - s;                                  // dlogp
    dl[e2] = tr.y - s;
}

extern "C" void kernel_launch(void* const* d_in, const int* in_sizes, int n_in,
                              void* d_out, int out_size, void* d_ws, size_t ws_size,
                              hipStream_t stream) {
    const float* t         = (const float*)d_in[0];
    const float* z         = (const float*)d_in[1];
    // d_in[2] = logp_z (unused by the reference outputs)
    const float* condition = (const float*)d_in[3];
    const float* hn_w1 = (const float*)d_in[4];
    const float* hn_b1 = (const float*)d_in[5];
    const float* hn_w2 = (const float*)d_in[6];
    const float* hn_b2 = (const float*)d_in[7];
    const float* hn_w3 = (const float*)d_in[8];
    const float* hn_b3 = (const float*)d_in[9];
    const float* cl_wz = (const float*)d_in[10];
    const float* cl_bz = (const float*)d_in[11];
    const float* cl_wc = (const float*)d_in[12];
    const float* cl_bc = (const float*)d_in[13];

    const int block = 256;
    const int grid = BATCH / 512;   // 512 blocks, 2 elements/thread
    fused_ode_kernel<<<grid, block, 0, stream>>>(
        t, hn_w1, hn_b1, hn_w2, hn_b2, hn_w3, hn_b3,
        z, (const float4*)condition,
        cl_wz, cl_bz, cl_wc, cl_bc, (float*)d_out);
}

// Round 4
// 20.146 us; speedup vs baseline: 1.0713x; 1.0713x over previous
//
#include <hip/hip_runtime.h>
#include <math.h>

#define D 2
#define HID 64
#define WIDTH 64
#define BATCH 262144
#define BLK 128  // WIDTH*D

typedef float v2f __attribute__((ext_vector_type(2)));

static __device__ __forceinline__ float fexp2(float x){ return __builtin_amdgcn_exp2f(x); }
static __device__ __forceinline__ float frcp(float x){ return __builtin_amdgcn_rcpf(x); }

// Packed Padé(5,4) tanh on clamp[-4,4]: x(945+105u+u^2)/(945+420u+15u^2), u=x^2.
// Max err ~2.3e-3 at |x|=4 (saturation), ~1e-4 interior.
static __device__ __forceinline__ v2f tanh_pk(v2f x) {
    v2f lo = {-4.f, -4.f}, hi = {4.f, 4.f};
    v2f t = __builtin_elementwise_min(__builtin_elementwise_max(x, lo), hi);
    v2f u = t * t;
    v2f num = t * (945.f + u * (105.f + u));
    v2f den = 945.f + u * (420.f + 15.f * u);
    v2f r; r.x = frcp(den.x); r.y = frcp(den.y);
    return num * r;
}

// ---------------- Kernel 1: hypernetwork (t -> params in d_ws) ----------------
// params layout (floats):
//   [4w+0..3]    = {W0, W1, Bb, WUs}   (w < 64)          -> 256 floats
//   [256+2w..+1] = {Us0, Us1}          (w < 64)          -> 128 floats
//   [384]        = sum_w WUs
__global__ __launch_bounds__(448) void hyper_kernel(
    const float* __restrict__ t,
    const float* __restrict__ w1, const float* __restrict__ b1,
    const float* __restrict__ w2, const float* __restrict__ b2,
    const float* __restrict__ w3, const float* __restrict__ b3,
    float* __restrict__ params)
{
    __shared__ float p1s[HID];
    __shared__ float p2s[HID];
    __shared__ float p3s[3*BLK + WIDTH];
    const int tid = threadIdx.x;
    const float L2E = 1.4426950408889634f;

    if (tid < HID) p1s[tid] = tanhf(t[0]*w1[tid] + b1[tid]);
    __syncthreads();

    if (tid < HID) {
        float a0=0.f, a1=0.f, a2=0.f, a3=0.f;
        const float4* row = (const float4*)(w2 + tid*HID);
        #pragma unroll 4
        for (int k = 0; k < HID/4; ++k) {
            float4 r = row[k];
            a0 = fmaf(p1s[4*k+0], r.x, a0);
            a1 = fmaf(p1s[4*k+1], r.y, a1);
            a2 = fmaf(p1s[4*k+2], r.z, a2);
            a3 = fmaf(p1s[4*k+3], r.w, a3);
        }
        p2s[tid] = tanhf(b2[tid] + ((a0+a1)+(a2+a3)));
    }
    __syncthreads();

    {   // 448 rows of w3, one per thread
        float a0=0.f, a1=0.f, a2=0.f, a3=0.f;
        const float4* row = (const float4*)(w3 + tid*HID);
        #pragma unroll 4
        for (int k = 0; k < HID/4; ++k) {
            float4 rv = row[k];
            a0 = fmaf(p2s[4*k+0], rv.x, a0);
            a1 = fmaf(p2s[4*k+1], rv.y, a1);
            a2 = fmaf(p2s[4*k+2], rv.z, a2);
            a3 = fmaf(p2s[4*k+3], rv.w, a3);
        }
        p3s[tid] = b3[tid] + ((a0+a1)+(a2+a3));
    }
    __syncthreads();

    if (tid < WIDTH) {   // wave 0
        const int w = tid;
        float W0 = p3s[2*w],        W1 = p3s[2*w+1];
        float U0 = p3s[BLK+2*w],    U1 = p3s[BLK+2*w+1];
        float G0 = p3s[2*BLK+2*w],  G1 = p3s[2*BLK+2*w+1];
        float Bb = p3s[3*BLK+w];
        U0 *= frcp(1.0f + fexp2(-G0*L2E));
        U1 *= frcp(1.0f + fexp2(-G1*L2E));
        float Us0 = U0 * (1.0f/WIDTH);
        float Us1 = U1 * (1.0f/WIDTH);
        float WUs = W0*Us0 + W1*Us1;
        ((float4*)params)[w] = make_float4(W0, W1, Bb, WUs);
        ((float2*)(params + 256))[w] = make_float2(Us0, Us1);
        float s = WUs;
        #pragma unroll
        for (int off = 32; off > 0; off >>= 1) s += __shfl_down(s, off);
        if (w == 0) params[384] = s;
    }
}

// ---------------- Kernel 2: batch phase — no LDS, no barriers ----------------
// 2 packed elements/thread: e1 = bid*512+tid, e2 = e1+256 (all streams coalesced).
// Params read via uniform-address loads -> scalar K-cache (s_load), zero LDS/VMEM-vector cost.
__global__ __launch_bounds__(256) void ode_kernel(
    const float* __restrict__ z,       // [B,2]
    const float4* __restrict__ c4,     // [B] condition rows
    const float* __restrict__ cl_wz, const float* __restrict__ cl_bz,
    const float* __restrict__ cl_wc, const float* __restrict__ cl_bc,
    const float* __restrict__ params,
    float* __restrict__ out)
{
    const int tid = threadIdx.x;
    const int e1 = blockIdx.x * 512 + tid;
    const int e2 = e1 + 256;

    float2 zA = ((const float2*)z)[e1];
    float2 zB = ((const float2*)z)[e2];
    float4 cA = c4[e1];
    float4 cB = c4[e2];

    // small uniform weights (uniform addresses -> scalar loads)
    float wz[8], wc[16], bbv[4];
    #pragma unroll
    for (int j = 0; j < 8;  ++j) wz[j] = cl_wz[j];
    #pragma unroll
    for (int j = 0; j < 16; ++j) wc[j] = cl_wc[j];
    #pragma unroll
    for (int j = 0; j < 4;  ++j) bbv[j] = cl_bz[j] + cl_bc[j];

    v2f zv0 = {zA.x, zB.x}, zv1 = {zA.y, zB.y};
    v2f cv0 = {cA.x, cB.x}, cv1 = {cA.y, cB.y};
    v2f cv2 = {cA.z, cB.z}, cv3 = {cA.w, cB.w};

    v2f act[4];
    #pragma unroll
    for (int j = 0; j < 4; ++j) {
        v2f a = zv0*wz[2*j] + zv1*wz[2*j+1] + bbv[j];
        a = a + cv0*wc[4*j] + cv1*wc[4*j+1] + cv2*wc[4*j+2] + cv3*wc[4*j+3];
        act[j] = a;
    }
    v2f th0 = tanh_pk(act[0]);
    v2f th1 = tanh_pk(act[1]);
    v2f sg0 = 0.5f + 0.5f*tanh_pk(act[2]*0.5f);
    v2f sg1 = 0.5f + 0.5f*tanh_pk(act[3]*0.5f);
    v2f zc0 = th0 * sg0;
    v2f zc1 = th1 * sg1;

    // condition copy out (coalesced, fire-and-forget)
    float4* oc = (float4*)(out + 3*(size_t)BATCH);
    oc[e1] = cA;
    oc[e2] = cB;

    const float4* __restrict__ PA = (const float4*)params;          // {W0,W1,Bb,WUs}
    const float2* __restrict__ PB = (const float2*)(params + 256);  // {Us0,Us1}

    v2f acc0 = {0.f,0.f}, acc1 = {0.f,0.f}, tr = {0.f,0.f};
    #pragma unroll 8
    for (int w = 0; w < WIDTH; ++w) {
        float4 pa = PA[w];   // uniform -> SGPRs
        float2 pb = PB[w];
        v2f pre = zc0*pa.x + zc1*pa.y + pa.z;
        v2f h = tanh_pk(pre);
        acc0 += h * pb.x;
        acc1 += h * pb.y;
        tr   += (h*h) * pa.w;
    }
    float s = params[384];

    ((float2*)out)[e1] = make_float2(acc0.x, acc1.x);   // dz_dt
    ((float2*)out)[e2] = make_float2(acc0.y, acc1.y);
    float* dl = out + 2*(size_t)BATCH;
    dl[e1] = tr.x - s;                                  // dlogp
    dl[e2] = tr.y - s;
}

extern "C" void kernel_launch(void* const* d_in, const int* in_sizes, int n_in,
                              void* d_out, int out_size, void* d_ws, size_t ws_size,
                              hipStream_t stream) {
    const float* t         = (const float*)d_in[0];
    const float* z         = (const float*)d_in[1];
    // d_in[2] = logp_z (unused by the reference outputs)
    const float* condition = (const float*)d_in[3];
    const float* hn_w1 = (const float*)d_in[4];
    const float* hn_b1 = (const float*)d_in[5];
    const float* hn_w2 = (const float*)d_in[6];
    const float* hn_b2 = (const float*)d_in[7];
    const float* hn_w3 = (const float*)d_in[8];
    const float* hn_b3 = (const float*)d_in[9];
    const float* cl_wz = (const float*)d_in[10];
    const float* cl_bz = (const float*)d_in[11];
    const float* cl_wc = (const float*)d_in[12];
    const float* cl_bc = (const float*)d_in[13];

    float* params = (float*)d_ws;   // 385 floats

    hyper_kernel<<<1, 448, 0, stream>>>(t, hn_w1, hn_b1, hn_w2, hn_b2, hn_w3, hn_b3, params);

    const int block = 256;
    const int grid = BATCH / 512;   // 512 blocks, 2 packed elements/thread
    ode_kernel<<<grid, block, 0, stream>>>(
        z, (const float4*)condition,
        cl_wz, cl_bz, cl_wc, cl_bc, params, (float*)d_out);
}

// Round 5
// 20.091 us; speedup vs baseline: 1.0743x; 1.0027x over previous
//
#include <hip/hip_runtime.h>
#include <math.h>

#define D 2
#define HID 64
#define WIDTH 64
#define BATCH 262144
#define BLK 128  // WIDTH*D

typedef float v2f __attribute__((ext_vector_type(2)));

static __device__ __forceinline__ float fexp2(float x){ return __builtin_amdgcn_exp2f(x); }
static __device__ __forceinline__ float frcp(float x){ return __builtin_amdgcn_rcpf(x); }

// Packed Padé(5,4) tanh on clamp[-4,4]: x(945+105u+u^2)/(945+420u+15u^2), u=x^2.
// Max err ~2.3e-3 at |x|=4 (saturation), ~1e-4 interior.
static __device__ __forceinline__ v2f tanh_pk(v2f x) {
    v2f lo = {-4.f, -4.f}, hi = {4.f, 4.f};
    v2f t = __builtin_elementwise_min(__builtin_elementwise_max(x, lo), hi);
    v2f u = t * t;
    v2f num = t * (945.f + u * (105.f + u));
    v2f den = 945.f + u * (420.f + 15.f * u);
    v2f r; r.x = frcp(den.x); r.y = frcp(den.y);
    return num * r;
}

// ---------------- Kernel 1: hypernetwork (t -> params in d_ws) ----------------
// All weight loads are issued into REGISTERS at kernel entry, so the whole
// 130 KB arrives under ONE HBM latency; the three dependent matvec stages then
// run on registers + LDS broadcasts only (no further global round-trips).
// params layout (floats):
//   [4w+0..3]    = {W0, W1, Bb, WUs}   (w < 64)          -> 256 floats
//   [256+2w..+1] = {Us0, Us1}          (w < 64)          -> 128 floats
//   [384]        = sum_w WUs
__global__ __launch_bounds__(448) void hyper_kernel(
    const float* __restrict__ t,
    const float* __restrict__ w1, const float* __restrict__ b1,
    const float* __restrict__ w2, const float* __restrict__ b2,
    const float* __restrict__ w3, const float* __restrict__ b3,
    float* __restrict__ params)
{
    __shared__ float p1s[HID];
    __shared__ float p2s[HID];
    __shared__ float p3s[3*BLK + WIDTH];
    const int tid = threadIdx.x;
    const float L2E = 1.4426950408889634f;

    // ---- bulk prefetch: every global load issued before any compute ----
    float4 w3r[16];
    {
        const float4* row = (const float4*)(w3 + tid*HID);
        #pragma unroll
        for (int k = 0; k < 16; ++k) w3r[k] = row[k];
    }
    float b3r = b3[tid];

    float4 w2r[16];
    float w1r = 0.f, b1r = 0.f, b2r = 0.f;
    if (tid < HID) {
        const float4* row = (const float4*)(w2 + tid*HID);
        #pragma unroll
        for (int k = 0; k < 16; ++k) w2r[k] = row[k];
        w1r = w1[tid]; b1r = b1[tid]; b2r = b2[tid];
    }
    float tv = t[0];

    // ---- stage 1: p1 = tanh(t*w1 + b1) ----
    if (tid < HID) p1s[tid] = tanhf(tv*w1r + b1r);
    __syncthreads();

    // ---- stage 2: p2 = tanh(w2 @ p1 + b2) (w2 row already in regs) ----
    if (tid < HID) {
        float a0=0.f, a1=0.f, a2=0.f, a3=0.f;
        #pragma unroll
        for (int k = 0; k < 16; ++k) {
            float4 r = w2r[k];
            a0 = fmaf(p1s[4*k+0], r.x, a0);
            a1 = fmaf(p1s[4*k+1], r.y, a1);
            a2 = fmaf(p1s[4*k+2], r.z, a2);
            a3 = fmaf(p1s[4*k+3], r.w, a3);
        }
        p2s[tid] = tanhf(b2r + ((a0+a1)+(a2+a3)));
    }
    __syncthreads();

    // ---- stage 3: p3 = w3 @ p2 + b3 (w3 row already in regs) ----
    {
        float a0=0.f, a1=0.f, a2=0.f, a3=0.f;
        #pragma unroll
        for (int k = 0; k < 16; ++k) {
            float4 rv = w3r[k];
            a0 = fmaf(p2s[4*k+0], rv.x, a0);
            a1 = fmaf(p2s[4*k+1], rv.y, a1);
            a2 = fmaf(p2s[4*k+2], rv.z, a2);
            a3 = fmaf(p2s[4*k+3], rv.w, a3);
        }
        p3s[tid] = b3r + ((a0+a1)+(a2+a3));
    }
    __syncthreads();

    // ---- epilogue: derive per-block params ----
    if (tid < WIDTH) {   // wave 0
        const int w = tid;
        float W0 = p3s[2*w],        W1 = p3s[2*w+1];
        float U0 = p3s[BLK+2*w],    U1 = p3s[BLK+2*w+1];
        float G0 = p3s[2*BLK+2*w],  G1 = p3s[2*BLK+2*w+1];
        float Bb = p3s[3*BLK+w];
        U0 *= frcp(1.0f + fexp2(-G0*L2E));
        U1 *= frcp(1.0f + fexp2(-G1*L2E));
        float Us0 = U0 * (1.0f/WIDTH);
        float Us1 = U1 * (1.0f/WIDTH);
        float WUs = W0*Us0 + W1*Us1;
        ((float4*)params)[w] = make_float4(W0, W1, Bb, WUs);
        ((float2*)(params + 256))[w] = make_float2(Us0, Us1);
        float s = WUs;
        #pragma unroll
        for (int off = 32; off > 0; off >>= 1) s += __shfl_down(s, off);
        if (w == 0) params[384] = s;
    }
}

// ---------------- Kernel 2: batch phase — no LDS, no barriers ----------------
// 2 packed elements/thread: e1 = bid*512+tid, e2 = e1+256 (all streams coalesced).
// Params read via uniform-address loads -> scalar K-cache (s_load), zero LDS/VMEM-vector cost.
__global__ __launch_bounds__(256) void ode_kernel(
    const float* __restrict__ z,       // [B,2]
    const float4* __restrict__ c4,     // [B] condition rows
    const float* __restrict__ cl_wz, const float* __restrict__ cl_bz,
    const float* __restrict__ cl_wc, const float* __restrict__ cl_bc,
    const float* __restrict__ params,
    float* __restrict__ out)
{
    const int tid = threadIdx.x;
    const int e1 = blockIdx.x * 512 + tid;
    const int e2 = e1 + 256;

    float2 zA = ((const float2*)z)[e1];
    float2 zB = ((const float2*)z)[e2];
    float4 cA = c4[e1];
    float4 cB = c4[e2];

    // small uniform weights (uniform addresses -> scalar loads)
    float wz[8], wc[16], bbv[4];
    #pragma unroll
    for (int j = 0; j < 8;  ++j) wz[j] = cl_wz[j];
    #pragma unroll
    for (int j = 0; j < 16; ++j) wc[j] = cl_wc[j];
    #pragma unroll
    for (int j = 0; j < 4;  ++j) bbv[j] = cl_bz[j] + cl_bc[j];

    v2f zv0 = {zA.x, zB.x}, zv1 = {zA.y, zB.y};
    v2f cv0 = {cA.x, cB.x}, cv1 = {cA.y, cB.y};
    v2f cv2 = {cA.z, cB.z}, cv3 = {cA.w, cB.w};

    v2f act[4];
    #pragma unroll
    for (int j = 0; j < 4; ++j) {
        v2f a = zv0*wz[2*j] + zv1*wz[2*j+1] + bbv[j];
        a = a + cv0*wc[4*j] + cv1*wc[4*j+1] + cv2*wc[4*j+2] + cv3*wc[4*j+3];
        act[j] = a;
    }
    v2f th0 = tanh_pk(act[0]);
    v2f th1 = tanh_pk(act[1]);
    v2f sg0 = 0.5f + 0.5f*tanh_pk(act[2]*0.5f);
    v2f sg1 = 0.5f + 0.5f*tanh_pk(act[3]*0.5f);
    v2f zc0 = th0 * sg0;
    v2f zc1 = th1 * sg1;

    // condition copy out (coalesced, fire-and-forget)
    float4* oc = (float4*)(out + 3*(size_t)BATCH);
    oc[e1] = cA;
    oc[e2] = cB;

    const float4* __restrict__ PA = (const float4*)params;          // {W0,W1,Bb,WUs}
    const float2* __restrict__ PB = (const float2*)(params + 256);  // {Us0,Us1}

    v2f acc0 = {0.f,0.f}, acc1 = {0.f,0.f}, tr = {0.f,0.f};
    #pragma unroll 16
    for (int w = 0; w < WIDTH; ++w) {
        float4 pa = PA[w];   // uniform -> SGPRs
        float2 pb = PB[w];
        v2f pre = zc0*pa.x + zc1*pa.y + pa.z;
        v2f h = tanh_pk(pre);
        acc0 += h * pb.x;
        acc1 += h * pb.y;
        tr   += (h*h) * pa.w;
    }
    float s = params[384];

    ((float2*)out)[e1] = make_float2(acc0.x, acc1.x);   // dz_dt
    ((float2*)out)[e2] = make_float2(acc0.y, acc1.y);
    float* dl = out + 2*(size_t)BATCH;
    dl[e1] = tr.x - s;                                  // dlogp
    dl[e2] = tr.y - s;
}

extern "C" void kernel_launch(void* const* d_in, const int* in_sizes, int n_in,
                              void* d_out, int out_size, void* d_ws, size_t ws_size,
                              hipStream_t stream) {
    const float* t         = (const float*)d_in[0];
    const float* z         = (const float*)d_in[1];
    // d_in[2] = logp_z (unused by the reference outputs)
    const float* condition = (const float*)d_in[3];
    const float* hn_w1 = (const float*)d_in[4];
    const float* hn_b1 = (const float*)d_in[5];
    const float* hn_w2 = (const float*)d_in[6];
    const float* hn_b2 = (const float*)d_in[7];
    const float* hn_w3 = (const float*)d_in[8];
    const float* hn_b3 = (const float*)d_in[9];
    const float* cl_wz = (const float*)d_in[10];
    const float* cl_bz = (const float*)d_in[11];
    const float* cl_wc = (const float*)d_in[12];
    const float* cl_bc = (const float*)d_in[13];

    float* params = (float*)d_ws;   // 385 floats

    hyper_kernel<<<1, 448, 0, stream>>>(t, hn_w1, hn_b1, hn_w2, hn_b2, hn_w3, hn_b3, params);

    const int block = 256;
    const int grid = BATCH / 512;   // 512 blocks, 2 packed elements/thread
    ode_kernel<<<grid, block, 0, stream>>>(
        z, (const float4*)condition,
        cl_wz, cl_bz, cl_wc, cl_bc, params, (float*)d_out);
}